// Round 1
// baseline (232.934 us; speedup 1.0000x reference)
//
#include <hip/hip_runtime.h>
#include <stdint.h>

// Problem constants
#define BB 4
#define LL 4096
#define CC 1024
#define HH 16
#define DD 64
#define MTOT (BB*LL)      // 16384
#define NQK 2048          // q(1024) + k(1024) columns

typedef __attribute__((ext_vector_type(4))) float f32x4;
typedef __attribute__((ext_vector_type(8))) short bf16x8;
typedef __attribute__((ext_vector_type(4))) unsigned short u16x4;
typedef unsigned short u16;

__device__ __forceinline__ u16 f2bf(float f) {
    union { float f; uint32_t u; } v; v.f = f;
    uint32_t r = v.u + 0x7fffu + ((v.u >> 16) & 1u);   // RNE
    return (u16)(r >> 16);
}
__device__ __forceinline__ float elu1(float s) {
    return s > 0.f ? s + 1.f : __expf(s);
}

// ---------------- cast x (fp32 -> bf16) ----------------
__global__ __launch_bounds__(256) void cast_x_kernel(const float* __restrict__ x,
                                                     u16* __restrict__ xb, int n4) {
    int idx = blockIdx.x * blockDim.x + threadIdx.x;
    int stride = gridDim.x * blockDim.x;
    const f32x4* x4 = (const f32x4*)x;
    u16x4* o4 = (u16x4*)xb;
    for (int i = idx; i < n4; i += stride) {
        f32x4 v = x4[i];
        u16x4 o;
        o.x = f2bf(v.x); o.y = f2bf(v.y); o.z = f2bf(v.z); o.w = f2bf(v.w);
        o4[i] = o;
    }
}

// ---------------- Wvs^T: wvst[h][k] = bf16( sum_d W_qkv[k][2048 + h*64 + d] ) ----------------
__global__ __launch_bounds__(256) void wsum_kernel(const float* __restrict__ Wqkv,
                                                   u16* __restrict__ wvst) {
    int k = blockIdx.x;              // 0..1023
    int t = threadIdx.x;             // 0..255, each loads 4 consecutive v-cols
    const f32x4* row = (const f32x4*)(Wqkv + (size_t)k * 3072 + 2048);
    f32x4 v = row[t];
    float s = v.x + v.y + v.z + v.w;
    s += __shfl_xor(s, 1); s += __shfl_xor(s, 2);
    s += __shfl_xor(s, 4); s += __shfl_xor(s, 8);
    if ((t & 15) == 0) {
        int h = t >> 4;              // 0..15
        wvst[h * 1024 + k] = f2bf(s);
    }
}

// ---------------- transpose+cast W_qkv cols 0..2047 -> wqkt[n][k] bf16 ----------------
__global__ void trans_wqk_kernel(const float* __restrict__ Wqkv, u16* __restrict__ wqkt) {
    __shared__ float tile[32][33];
    int n0 = blockIdx.x * 32;        // 64 blocks
    int k0 = blockIdx.y * 32;        // 32 blocks
    int tx = threadIdx.x;            // 0..31
    int ty = threadIdx.y;            // 0..7
    #pragma unroll
    for (int i = 0; i < 32; i += 8)
        tile[ty + i][tx] = Wqkv[(size_t)(k0 + ty + i) * 3072 + n0 + tx];
    __syncthreads();
    #pragma unroll
    for (int i = 0; i < 32; i += 8)
        wqkt[(size_t)(n0 + ty + i) * 1024 + k0 + tx] = f2bf(tile[tx][ty + i]);
}

// ---------------- vsum[row][h] = sum_k x[row,k] * Wvs[k,h]  (tiny MFMA GEMM) ----------------
__global__ __launch_bounds__(256) void vsum_kernel(const u16* __restrict__ xb,
                                                   const u16* __restrict__ wvst,
                                                   float* __restrict__ vsum) {
    int lane = threadIdx.x & 63;
    int w = threadIdx.x >> 6;
    int m0 = blockIdx.x * 64 + w * 16;          // 256 blocks * 4 waves * 16 rows = 16384
    int r = lane & 15, g = lane >> 4;
    f32x4 acc = {0.f, 0.f, 0.f, 0.f};
    const bf16x8* ap = (const bf16x8*)(xb + (size_t)(m0 + r) * 1024 + g * 8);
    const bf16x8* bp = (const bf16x8*)(wvst + (size_t)r * 1024 + g * 8);
    #pragma unroll 4
    for (int kt = 0; kt < 1024; kt += 32) {
        bf16x8 a = ap[kt >> 3];
        bf16x8 b = bp[kt >> 3];
        acc = __builtin_amdgcn_mfma_f32_16x16x32_bf16(a, b, acc, 0, 0, 0);
    }
    #pragma unroll
    for (int ri = 0; ri < 4; ++ri)
        vsum[(size_t)(m0 + g * 4 + ri) * 16 + r] = acc[ri];
}

// ---------------- main GEMM: [16384,1024]bf16 @ wqkt^T -> fused qsum / kvrow ----------------
__global__ __launch_bounds__(256) void gemm_qk_kernel(const u16* __restrict__ A,
                                                      const u16* __restrict__ Bt,
                                                      const float* __restrict__ vsum,
                                                      float* __restrict__ qsum,
                                                      float* __restrict__ kvsum) {
    __shared__ u16 As[128 * 64];
    __shared__ u16 Bs[128 * 64];
    const int tid = threadIdx.x;
    const int lane = tid & 63;
    const int wid = tid >> 6;
    const int wm = wid >> 1, wn = wid & 1;      // 2x2 waves, each 64x64
    const int m0 = blockIdx.x * 128;
    const int n0 = blockIdx.y * 128;
    const int r = lane & 15, g = lane >> 4;

    f32x4 acc[4][4];
    #pragma unroll
    for (int i = 0; i < 4; ++i)
        #pragma unroll
        for (int j = 0; j < 4; ++j)
            acc[i][j] = (f32x4){0.f, 0.f, 0.f, 0.f};

    // staging geometry: chunk i covers elements [i*2048 + tid*8, +8)
    const int srow = tid >> 3;                   // 0..31
    const int scol = (tid & 7) * 8;              // 0..56
    const u16* aBase = A + (size_t)(m0 + srow) * 1024 + scol;
    const u16* bBase = Bt + (size_t)(n0 + srow) * 1024 + scol;
    u16* aDst = As + tid * 8;
    u16* bDst = Bs + tid * 8;

    for (int kt = 0; kt < 1024; kt += 64) {
        #pragma unroll
        for (int i = 0; i < 4; ++i) {
            __builtin_amdgcn_global_load_lds(
                (const __attribute__((address_space(1))) void*)(aBase + (size_t)i * 32 * 1024 + kt),
                (__attribute__((address_space(3))) void*)(aDst + i * 2048), 16, 0, 0);
            __builtin_amdgcn_global_load_lds(
                (const __attribute__((address_space(1))) void*)(bBase + (size_t)i * 32 * 1024 + kt),
                (__attribute__((address_space(3))) void*)(bDst + i * 2048), 16, 0, 0);
        }
        __syncthreads();
        #pragma unroll
        for (int ks = 0; ks < 2; ++ks) {
            const int kof = ks * 32 + g * 8;
            bf16x8 av[4], bv[4];
            #pragma unroll
            for (int mi = 0; mi < 4; ++mi)
                av[mi] = *(const bf16x8*)(As + (wm * 64 + mi * 16 + r) * 64 + kof);
            #pragma unroll
            for (int ni = 0; ni < 4; ++ni)
                bv[ni] = *(const bf16x8*)(Bs + (wn * 64 + ni * 16 + r) * 64 + kof);
            #pragma unroll
            for (int mi = 0; mi < 4; ++mi)
                #pragma unroll
                for (int ni = 0; ni < 4; ++ni)
                    acc[mi][ni] = __builtin_amdgcn_mfma_f32_16x16x32_bf16(av[mi], bv[ni], acc[mi][ni], 0, 0, 0);
        }
        __syncthreads();
    }

    // fused epilogue. C/D layout: col = ni*16 + r, row = mi*16 + g*4 + rr (within wave 64x64 tile)
    if (blockIdx.y < 8) {
        // q region: qsum[row][h] = sum of elu1 over the head's 64 cols (exactly this wave's cols)
        const int h = blockIdx.y * 2 + wn;
        #pragma unroll
        for (int mi = 0; mi < 4; ++mi) {
            #pragma unroll
            for (int rr = 0; rr < 4; ++rr) {
                float s = elu1(acc[mi][0][rr]) + elu1(acc[mi][1][rr]) +
                          elu1(acc[mi][2][rr]) + elu1(acc[mi][3][rr]);
                s += __shfl_xor(s, 1); s += __shfl_xor(s, 2);
                s += __shfl_xor(s, 4); s += __shfl_xor(s, 8);
                if (r == 0)
                    qsum[(size_t)(m0 + wm * 64 + mi * 16 + g * 4 + rr) * 16 + h] = s;
            }
        }
    } else {
        // k region: kvrow[b][h][d] += sum over rows of elu1(k) * vsum[row][h]
        const int h = (blockIdx.y - 8) * 2 + wn;
        const int b = m0 >> 12;
        float kvp[4] = {0.f, 0.f, 0.f, 0.f};
        #pragma unroll
        for (int mi = 0; mi < 4; ++mi) {
            #pragma unroll
            for (int rr = 0; rr < 4; ++rr) {
                const int row = m0 + wm * 64 + mi * 16 + g * 4 + rr;
                const float vs = vsum[(size_t)row * 16 + h];
                #pragma unroll
                for (int ni = 0; ni < 4; ++ni)
                    kvp[ni] += elu1(acc[mi][ni][rr]) * vs;
            }
        }
        #pragma unroll
        for (int ni = 0; ni < 4; ++ni) {
            kvp[ni] += __shfl_xor(kvp[ni], 16);
            kvp[ni] += __shfl_xor(kvp[ni], 32);
        }
        if (g == 0) {
            #pragma unroll
            for (int ni = 0; ni < 4; ++ni)
                atomicAdd(&kvsum[((size_t)b * 16 + h) * 64 + ni * 16 + r], kvp[ni]);
        }
    }
}

// ---------------- Wkv[b][h][c] = sum_d kvrow[b][h][d] * W_proj[h*64+d][c] ----------------
__global__ __launch_bounds__(256) void wkv_kernel(const float* __restrict__ kvsum,
                                                  const float* __restrict__ Wproj,
                                                  float* __restrict__ wkv) {
    __shared__ float kv[64];
    const int bh = blockIdx.y;                     // 0..63
    const int c = blockIdx.x * 256 + threadIdx.x;  // 0..1023
    if (threadIdx.x < 64) kv[threadIdx.x] = kvsum[bh * 64 + threadIdx.x];
    __syncthreads();
    const int h = bh & 15;
    float s = 0.f;
    #pragma unroll 8
    for (int d = 0; d < 64; ++d)
        s += kv[d] * Wproj[(size_t)(h * 64 + d) * 1024 + c];
    wkv[(size_t)bh * 1024 + c] = s;
}

// ---------------- y[row][c] = b_proj[c] + sum_h qsum[row][h] * Wkv[b][h][c] ----------------
__global__ __launch_bounds__(256) void final_kernel(const float* __restrict__ qsum,
                                                    const float* __restrict__ wkv,
                                                    const float* __restrict__ bproj,
                                                    float* __restrict__ y) {
    __shared__ float qs[4][16];
    const int r0 = blockIdx.x * 4;                 // 4096 blocks, 4 rows each
    const int t = threadIdx.x;
    if (t < 64) qs[t >> 4][t & 15] = qsum[(size_t)(r0 + (t >> 4)) * 16 + (t & 15)];
    __syncthreads();
    const int b = r0 >> 12;
    const f32x4* wk4 = (const f32x4*)(wkv + (size_t)b * 16 * 1024);
    f32x4 bp = ((const f32x4*)bproj)[t];
    f32x4 a0 = bp, a1 = bp, a2 = bp, a3 = bp;
    #pragma unroll
    for (int h = 0; h < 16; ++h) {
        f32x4 w = wk4[h * 256 + t];
        a0 += qs[0][h] * w;
        a1 += qs[1][h] * w;
        a2 += qs[2][h] * w;
        a3 += qs[3][h] * w;
    }
    f32x4* y4 = (f32x4*)y;
    y4[(size_t)(r0 + 0) * 256 + t] = a0;
    y4[(size_t)(r0 + 1) * 256 + t] = a1;
    y4[(size_t)(r0 + 2) * 256 + t] = a2;
    y4[(size_t)(r0 + 3) * 256 + t] = a3;
}

extern "C" void kernel_launch(void* const* d_in, const int* in_sizes, int n_in,
                              void* d_out, int out_size, void* d_ws, size_t ws_size,
                              hipStream_t stream) {
    const float* x     = (const float*)d_in[0];   // [4,4096,1024]
    const float* Wqkv  = (const float*)d_in[1];   // [1024,3072]
    const float* Wproj = (const float*)d_in[2];   // [1024,1024]
    const float* bproj = (const float*)d_in[3];   // [1024]
    float* y = (float*)d_out;                     // [4,4096,1024]

    char* ws = (char*)d_ws;
    u16*   xb    = (u16*)(ws);                    // 16384*1024*2 = 33554432
    u16*   wqkt  = (u16*)(ws + 33554432);         // 2048*1024*2  =  4194304
    u16*   wvst  = (u16*)(ws + 37748736);         // 16*1024*2    =    32768
    float* vsum  = (float*)(ws + 37781504);       // 16384*16*4   =  1048576
    float* qsum  = (float*)(ws + 38830080);       // 16384*16*4   =  1048576
    float* kvsum = (float*)(ws + 39878656);       // 4*16*64*4    =    16384
    float* wkv   = (float*)(ws + 39895040);       // 4*16*1024*4  =   262144
    // total 40157184 bytes (~38.3 MiB)

    hipMemsetAsync(kvsum, 0, 4096 * sizeof(float), stream);

    cast_x_kernel<<<4096, 256, 0, stream>>>(x, xb, (MTOT * CC) / 4);
    wsum_kernel<<<1024, 256, 0, stream>>>(Wqkv, wvst);
    trans_wqk_kernel<<<dim3(64, 32), dim3(32, 8), 0, stream>>>(Wqkv, wqkt);
    vsum_kernel<<<256, 256, 0, stream>>>(xb, wvst, vsum);
    gemm_qk_kernel<<<dim3(128, 16), 256, 0, stream>>>(xb, wqkt, vsum, qsum, kvsum);
    wkv_kernel<<<dim3(4, 64), 256, 0, stream>>>(kvsum, Wproj, wkv);
    final_kernel<<<4096, 256, 0, stream>>>(qsum, wkv, bproj, y);
}

// Round 2
// 158.218 us; speedup vs baseline: 1.4722x; 1.4722x over previous
//
#include <hip/hip_runtime.h>
#include <stdint.h>

// Problem constants
#define BB 4
#define LL 4096
#define CC 1024
#define HH 16
#define DD 64
#define MTOT (BB*LL)      // 16384
#define NQK 2048          // q(1024) + k(1024) columns

typedef __attribute__((ext_vector_type(4))) float f32x4;
typedef __attribute__((ext_vector_type(8))) short bf16x8;
typedef __attribute__((ext_vector_type(4))) unsigned short u16x4;
typedef unsigned short u16;

__device__ __forceinline__ u16 f2bf(float f) {
    union { float f; uint32_t u; } v; v.f = f;
    uint32_t r = v.u + 0x7fffu + ((v.u >> 16) & 1u);   // RNE
    return (u16)(r >> 16);
}
__device__ __forceinline__ float elu1(float s) {
    return s > 0.f ? s + 1.f : __expf(s);
}

// ---------------- cast x (fp32 -> bf16) ----------------
__global__ __launch_bounds__(256) void cast_x_kernel(const float* __restrict__ x,
                                                     u16* __restrict__ xb, int n4) {
    int idx = blockIdx.x * blockDim.x + threadIdx.x;
    int stride = gridDim.x * blockDim.x;
    const f32x4* x4 = (const f32x4*)x;
    u16x4* o4 = (u16x4*)xb;
    for (int i = idx; i < n4; i += stride) {
        f32x4 v = x4[i];
        u16x4 o;
        o.x = f2bf(v.x); o.y = f2bf(v.y); o.z = f2bf(v.z); o.w = f2bf(v.w);
        o4[i] = o;
    }
}

// ---------------- Wvs^T: wvst[h][k] = bf16( sum_d W_qkv[k][2048 + h*64 + d] ) ----------------
__global__ __launch_bounds__(256) void wsum_kernel(const float* __restrict__ Wqkv,
                                                   u16* __restrict__ wvst) {
    int k = blockIdx.x;              // 0..1023
    int t = threadIdx.x;             // 0..255, each loads 4 consecutive v-cols
    const f32x4* row = (const f32x4*)(Wqkv + (size_t)k * 3072 + 2048);
    f32x4 v = row[t];
    float s = v.x + v.y + v.z + v.w;
    s += __shfl_xor(s, 1); s += __shfl_xor(s, 2);
    s += __shfl_xor(s, 4); s += __shfl_xor(s, 8);
    if ((t & 15) == 0) {
        int h = t >> 4;              // 0..15
        wvst[h * 1024 + k] = f2bf(s);
    }
}

// ---------------- transpose+cast W_qkv cols 0..2047 -> wqkt[n][k] bf16 ----------------
__global__ void trans_wqk_kernel(const float* __restrict__ Wqkv, u16* __restrict__ wqkt) {
    __shared__ float tile[32][33];
    int n0 = blockIdx.x * 32;        // 64 blocks
    int k0 = blockIdx.y * 32;        // 32 blocks
    int tx = threadIdx.x;            // 0..31
    int ty = threadIdx.y;            // 0..7
    #pragma unroll
    for (int i = 0; i < 32; i += 8)
        tile[ty + i][tx] = Wqkv[(size_t)(k0 + ty + i) * 3072 + n0 + tx];
    __syncthreads();
    #pragma unroll
    for (int i = 0; i < 32; i += 8)
        wqkt[(size_t)(n0 + ty + i) * 1024 + k0 + tx] = f2bf(tile[tx][ty + i]);
}

// ---------------- vsum[row][h] = sum_k x[row,k] * Wvs[k,h]  (tiny MFMA GEMM) ----------------
__global__ __launch_bounds__(256) void vsum_kernel(const u16* __restrict__ xb,
                                                   const u16* __restrict__ wvst,
                                                   float* __restrict__ vsum) {
    int lane = threadIdx.x & 63;
    int w = threadIdx.x >> 6;
    int m0 = blockIdx.x * 64 + w * 16;          // 256 blocks * 4 waves * 16 rows = 16384
    int r = lane & 15, g = lane >> 4;
    f32x4 acc = {0.f, 0.f, 0.f, 0.f};
    const bf16x8* ap = (const bf16x8*)(xb + (size_t)(m0 + r) * 1024 + g * 8);
    const bf16x8* bp = (const bf16x8*)(wvst + (size_t)r * 1024 + g * 8);
    #pragma unroll 4
    for (int kt = 0; kt < 1024; kt += 32) {
        bf16x8 a = ap[kt >> 3];
        bf16x8 b = bp[kt >> 3];
        acc = __builtin_amdgcn_mfma_f32_16x16x32_bf16(a, b, acc, 0, 0, 0);
    }
    #pragma unroll
    for (int ri = 0; ri < 4; ++ri)
        vsum[(size_t)(m0 + g * 4 + ri) * 16 + r] = acc[ri];
}

// ---------------- main GEMM: [16384,1024]bf16 @ wqkt^T -> fused qsum / kvrow ----------------
// 2-phase double-buffered (T3 minimum recipe): stage next K-tile before computing
// current; single __syncthreads per K-step (its implicit vmcnt(0) lands after MFMA).
__global__ __launch_bounds__(256) void gemm_qk_kernel(const u16* __restrict__ A,
                                                      const u16* __restrict__ Bt,
                                                      const float* __restrict__ vsum,
                                                      float* __restrict__ qsum,
                                                      float* __restrict__ kvsum) {
    __shared__ u16 As[2][128 * 64];
    __shared__ u16 Bs[2][128 * 64];
    const int tid = threadIdx.x;
    const int lane = tid & 63;
    const int wid = tid >> 6;
    const int wm = wid >> 1, wn = wid & 1;      // 2x2 waves, each 64x64
    const int m0 = blockIdx.x * 128;
    const int n0 = blockIdx.y * 128;
    const int r = lane & 15, g = lane >> 4;

    f32x4 acc[4][4];
    #pragma unroll
    for (int i = 0; i < 4; ++i)
        #pragma unroll
        for (int j = 0; j < 4; ++j)
            acc[i][j] = (f32x4){0.f, 0.f, 0.f, 0.f};

    // staging geometry: chunk i covers elements [i*2048 + tid*8, +8)
    const int srow = tid >> 3;                   // 0..31
    const int scol = (tid & 7) * 8;              // 0..56
    const u16* aBase = A + (size_t)(m0 + srow) * 1024 + scol;
    const u16* bBase = Bt + (size_t)(n0 + srow) * 1024 + scol;

#define STAGE(buf, kt)                                                                         \
    do {                                                                                       \
        u16* aD = As[buf] + tid * 8;                                                           \
        u16* bD = Bs[buf] + tid * 8;                                                           \
        _Pragma("unroll")                                                                      \
        for (int i = 0; i < 4; ++i) {                                                          \
            __builtin_amdgcn_global_load_lds(                                                  \
                (const __attribute__((address_space(1))) void*)(aBase + (size_t)i * 32 * 1024 + (kt)), \
                (__attribute__((address_space(3))) void*)(aD + i * 2048), 16, 0, 0);           \
            __builtin_amdgcn_global_load_lds(                                                  \
                (const __attribute__((address_space(1))) void*)(bBase + (size_t)i * 32 * 1024 + (kt)), \
                (__attribute__((address_space(3))) void*)(bD + i * 2048), 16, 0, 0);           \
        }                                                                                      \
    } while (0)

    // prologue: stage K-tile 0 into buffer 0
    STAGE(0, 0);
    __syncthreads();                              // compiler emits vmcnt(0) before barrier

    int cur = 0;
    for (int kt = 0; kt < 1024; kt += 64) {
        const int nxt = kt + 64;
        if (nxt < 1024)
            STAGE(cur ^ 1, nxt);                  // prefetch next tile (in flight during MFMA)

        #pragma unroll
        for (int ks = 0; ks < 2; ++ks) {
            const int kof = ks * 32 + g * 8;
            bf16x8 av[4], bv[4];
            #pragma unroll
            for (int mi = 0; mi < 4; ++mi)
                av[mi] = *(const bf16x8*)(As[cur] + (wm * 64 + mi * 16 + r) * 64 + kof);
            #pragma unroll
            for (int ni = 0; ni < 4; ++ni)
                bv[ni] = *(const bf16x8*)(Bs[cur] + (wn * 64 + ni * 16 + r) * 64 + kof);
            #pragma unroll
            for (int mi = 0; mi < 4; ++mi)
                #pragma unroll
                for (int ni = 0; ni < 4; ++ni)
                    acc[mi][ni] = __builtin_amdgcn_mfma_f32_16x16x32_bf16(av[mi], bv[ni], acc[mi][ni], 0, 0, 0);
        }

        if (nxt < 1024) {
            // one barrier per K-step: ensures (a) prefetched tile landed (vmcnt drain
            // happens AFTER the MFMA block above), (b) all waves done reading As[cur]
            // before next iteration stages over it.
            __syncthreads();
            cur ^= 1;
        }
    }
#undef STAGE

    // fused epilogue. C/D layout: col = ni*16 + r, row = mi*16 + g*4 + rr (within wave 64x64 tile)
    if (blockIdx.y < 8) {
        // q region: qsum[row][h] = sum of elu1 over the head's 64 cols (exactly this wave's cols)
        const int h = blockIdx.y * 2 + wn;
        #pragma unroll
        for (int mi = 0; mi < 4; ++mi) {
            #pragma unroll
            for (int rr = 0; rr < 4; ++rr) {
                float s = elu1(acc[mi][0][rr]) + elu1(acc[mi][1][rr]) +
                          elu1(acc[mi][2][rr]) + elu1(acc[mi][3][rr]);
                s += __shfl_xor(s, 1); s += __shfl_xor(s, 2);
                s += __shfl_xor(s, 4); s += __shfl_xor(s, 8);
                if (r == 0)
                    qsum[(size_t)(m0 + wm * 64 + mi * 16 + g * 4 + rr) * 16 + h] = s;
            }
        }
    } else {
        // k region: kvrow[b][h][d] += sum over rows of elu1(k) * vsum[row][h]
        const int h = (blockIdx.y - 8) * 2 + wn;
        const int b = m0 >> 12;
        float kvp[4] = {0.f, 0.f, 0.f, 0.f};
        #pragma unroll
        for (int mi = 0; mi < 4; ++mi) {
            #pragma unroll
            for (int rr = 0; rr < 4; ++rr) {
                const int row = m0 + wm * 64 + mi * 16 + g * 4 + rr;
                const float vs = vsum[(size_t)row * 16 + h];
                #pragma unroll
                for (int ni = 0; ni < 4; ++ni)
                    kvp[ni] += elu1(acc[mi][ni][rr]) * vs;
            }
        }
        #pragma unroll
        for (int ni = 0; ni < 4; ++ni) {
            kvp[ni] += __shfl_xor(kvp[ni], 16);
            kvp[ni] += __shfl_xor(kvp[ni], 32);
        }
        if (g == 0) {
            #pragma unroll
            for (int ni = 0; ni < 4; ++ni)
                atomicAdd(&kvsum[((size_t)b * 16 + h) * 64 + ni * 16 + r], kvp[ni]);
        }
    }
}

// ---------------- Wkv[b][h][c] = sum_d kvrow[b][h][d] * W_proj[h*64+d][c] ----------------
__global__ __launch_bounds__(256) void wkv_kernel(const float* __restrict__ kvsum,
                                                  const float* __restrict__ Wproj,
                                                  float* __restrict__ wkv) {
    __shared__ float kv[64];
    const int bh = blockIdx.y;                     // 0..63
    const int c = blockIdx.x * 256 + threadIdx.x;  // 0..1023
    if (threadIdx.x < 64) kv[threadIdx.x] = kvsum[bh * 64 + threadIdx.x];
    __syncthreads();
    const int h = bh & 15;
    float s = 0.f;
    #pragma unroll 8
    for (int d = 0; d < 64; ++d)
        s += kv[d] * Wproj[(size_t)(h * 64 + d) * 1024 + c];
    wkv[(size_t)bh * 1024 + c] = s;
}

// ---------------- y[row][c] = b_proj[c] + sum_h qsum[row][h] * Wkv[b][h][c] ----------------
__global__ __launch_bounds__(256) void final_kernel(const float* __restrict__ qsum,
                                                    const float* __restrict__ wkv,
                                                    const float* __restrict__ bproj,
                                                    float* __restrict__ y) {
    __shared__ float qs[4][16];
    const int r0 = blockIdx.x * 4;                 // 4096 blocks, 4 rows each
    const int t = threadIdx.x;
    if (t < 64) qs[t >> 4][t & 15] = qsum[(size_t)(r0 + (t >> 4)) * 16 + (t & 15)];
    __syncthreads();
    const int b = r0 >> 12;
    const f32x4* wk4 = (const f32x4*)(wkv + (size_t)b * 16 * 1024);
    f32x4 bp = ((const f32x4*)bproj)[t];
    f32x4 a0 = bp, a1 = bp, a2 = bp, a3 = bp;
    #pragma unroll
    for (int h = 0; h < 16; ++h) {
        f32x4 w = wk4[h * 256 + t];
        a0 += qs[0][h] * w;
        a1 += qs[1][h] * w;
        a2 += qs[2][h] * w;
        a3 += qs[3][h] * w;
    }
    f32x4* y4 = (f32x4*)y;
    y4[(size_t)(r0 + 0) * 256 + t] = a0;
    y4[(size_t)(r0 + 1) * 256 + t] = a1;
    y4[(size_t)(r0 + 2) * 256 + t] = a2;
    y4[(size_t)(r0 + 3) * 256 + t] = a3;
}

extern "C" void kernel_launch(void* const* d_in, const int* in_sizes, int n_in,
                              void* d_out, int out_size, void* d_ws, size_t ws_size,
                              hipStream_t stream) {
    const float* x     = (const float*)d_in[0];   // [4,4096,1024]
    const float* Wqkv  = (const float*)d_in[1];   // [1024,3072]
    const float* Wproj = (const float*)d_in[2];   // [1024,1024]
    const float* bproj = (const float*)d_in[3];   // [1024]
    float* y = (float*)d_out;                     // [4,4096,1024]

    char* ws = (char*)d_ws;
    u16*   xb    = (u16*)(ws);                    // 16384*1024*2 = 33554432
    u16*   wqkt  = (u16*)(ws + 33554432);         // 2048*1024*2  =  4194304
    u16*   wvst  = (u16*)(ws + 37748736);         // 16*1024*2    =    32768
    float* vsum  = (float*)(ws + 37781504);       // 16384*16*4   =  1048576
    float* qsum  = (float*)(ws + 38830080);       // 16384*16*4   =  1048576
    float* kvsum = (float*)(ws + 39878656);       // 4*16*64*4    =    16384
    float* wkv   = (float*)(ws + 39895040);       // 4*16*1024*4  =   262144
    // total 40157184 bytes (~38.3 MiB)

    hipMemsetAsync(kvsum, 0, 4096 * sizeof(float), stream);

    cast_x_kernel<<<4096, 256, 0, stream>>>(x, xb, (MTOT * CC) / 4);
    wsum_kernel<<<1024, 256, 0, stream>>>(Wqkv, wvst);
    trans_wqk_kernel<<<dim3(64, 32), dim3(32, 8), 0, stream>>>(Wqkv, wqkt);
    vsum_kernel<<<256, 256, 0, stream>>>(xb, wvst, vsum);
    gemm_qk_kernel<<<dim3(128, 16), 256, 0, stream>>>(xb, wqkt, vsum, qsum, kvsum);
    wkv_kernel<<<dim3(4, 64), 256, 0, stream>>>(kvsum, Wproj, wkv);
    final_kernel<<<4096, 256, 0, stream>>>(qsum, wkv, bproj, y);
}

// Round 3
// 134.426 us; speedup vs baseline: 1.7328x; 1.1770x over previous
//
#include <hip/hip_runtime.h>
#include <stdint.h>

// Problem constants
#define BB 4
#define LL 4096
#define CC 1024
#define HH 16
#define DD 64
#define MTOT (BB*LL)      // 16384
#define NQK 2048          // q(1024) + k(1024) columns

typedef __attribute__((ext_vector_type(4))) float f32x4;
typedef __attribute__((ext_vector_type(8))) short bf16x8;
typedef __attribute__((ext_vector_type(4))) unsigned short u16x4;
typedef unsigned short u16;

__device__ __forceinline__ u16 f2bf(float f) {
    union { float f; uint32_t u; } v; v.f = f;
    uint32_t r = v.u + 0x7fffu + ((v.u >> 16) & 1u);   // RNE
    return (u16)(r >> 16);
}
__device__ __forceinline__ float elu1(float s) {
    return s > 0.f ? s + 1.f : __expf(s);
}

// ---------------- cast x (fp32 -> bf16) ----------------
__global__ __launch_bounds__(256) void cast_x_kernel(const float* __restrict__ x,
                                                     u16* __restrict__ xb, int n4) {
    int idx = blockIdx.x * blockDim.x + threadIdx.x;
    int stride = gridDim.x * blockDim.x;
    const f32x4* x4 = (const f32x4*)x;
    u16x4* o4 = (u16x4*)xb;
    for (int i = idx; i < n4; i += stride) {
        f32x4 v = x4[i];
        u16x4 o;
        o.x = f2bf(v.x); o.y = f2bf(v.y); o.z = f2bf(v.z); o.w = f2bf(v.w);
        o4[i] = o;
    }
}

// ---------------- Wvs^T: wvst[h][k] = bf16( sum_d W_qkv[k][2048 + h*64 + d] ) ----------------
__global__ __launch_bounds__(256) void wsum_kernel(const float* __restrict__ Wqkv,
                                                   u16* __restrict__ wvst) {
    int k = blockIdx.x;              // 0..1023
    int t = threadIdx.x;             // 0..255, each loads 4 consecutive v-cols
    const f32x4* row = (const f32x4*)(Wqkv + (size_t)k * 3072 + 2048);
    f32x4 v = row[t];
    float s = v.x + v.y + v.z + v.w;
    s += __shfl_xor(s, 1); s += __shfl_xor(s, 2);
    s += __shfl_xor(s, 4); s += __shfl_xor(s, 8);
    if ((t & 15) == 0) {
        int h = t >> 4;              // 0..15
        wvst[h * 1024 + k] = f2bf(s);
    }
}

// ---------------- transpose+cast W_qkv cols 0..2047 -> wqkt[n][k] bf16 ----------------
__global__ void trans_wqk_kernel(const float* __restrict__ Wqkv, u16* __restrict__ wqkt) {
    __shared__ float tile[32][33];
    int n0 = blockIdx.x * 32;        // 64 blocks
    int k0 = blockIdx.y * 32;        // 32 blocks
    int tx = threadIdx.x;            // 0..31
    int ty = threadIdx.y;            // 0..7
    #pragma unroll
    for (int i = 0; i < 32; i += 8)
        tile[ty + i][tx] = Wqkv[(size_t)(k0 + ty + i) * 3072 + n0 + tx];
    __syncthreads();
    #pragma unroll
    for (int i = 0; i < 32; i += 8)
        wqkt[(size_t)(n0 + ty + i) * 1024 + k0 + tx] = f2bf(tile[tx][ty + i]);
}

// ---------------- vsum[row][h] = sum_k x[row,k] * Wvs[k,h]  (tiny MFMA GEMM) ----------------
__global__ __launch_bounds__(256) void vsum_kernel(const u16* __restrict__ xb,
                                                   const u16* __restrict__ wvst,
                                                   float* __restrict__ vsum) {
    int lane = threadIdx.x & 63;
    int w = threadIdx.x >> 6;
    int m0 = blockIdx.x * 64 + w * 16;          // 256 blocks * 4 waves * 16 rows = 16384
    int r = lane & 15, g = lane >> 4;
    f32x4 acc = {0.f, 0.f, 0.f, 0.f};
    const bf16x8* ap = (const bf16x8*)(xb + (size_t)(m0 + r) * 1024 + g * 8);
    const bf16x8* bp = (const bf16x8*)(wvst + (size_t)r * 1024 + g * 8);
    #pragma unroll 4
    for (int kt = 0; kt < 1024; kt += 32) {
        bf16x8 a = ap[kt >> 3];
        bf16x8 b = bp[kt >> 3];
        acc = __builtin_amdgcn_mfma_f32_16x16x32_bf16(a, b, acc, 0, 0, 0);
    }
    #pragma unroll
    for (int ri = 0; ri < 4; ++ri)
        vsum[(size_t)(m0 + g * 4 + ri) * 16 + r] = acc[ri];
}

// ---------------- main GEMM: 256x256 tile, BK=64, 8-phase schedule ----------------
// T1 XCD swizzle + T2 slot^row&7 LDS swizzle + T3/T4 counted vmcnt + T5 setprio.
// 8 waves (2M x 4N), per-wave 128x64 output. LDS 128 KiB: [2 dbuf][2 half][128][64] x {A,B}.
// Stage schedule (group g computes K-tile g from buf g&1):
//   ph1: read A[mh0]+B[nh0]; stage B-half0(g+1)->buf dn; mfma(mh0,nh0)
//   ph2: read B[nh1];        stage B-half1(g+1)->buf dn; mfma(mh0,nh1)
//   ph3: read A[mh1];                                    mfma(mh1,nh1)
//   ph4: stage A-half0,1(g+2)->buf d; mfma(mh1,nh0); vmcnt(4); barrier
// Safety: every stage-issue is barrier-after the last ds_read of the region it
// overwrites; vmcnt(4) leaves exactly the 2 ph4 half-tiles in flight.
__global__ __launch_bounds__(512, 2) void gemm_qk_kernel(const u16* __restrict__ A,
                                                         const u16* __restrict__ Bt,
                                                         const float* __restrict__ vsum,
                                                         float* __restrict__ qsum,
                                                         float* __restrict__ kvsum) {
    __shared__ u16 As[2][2][128 * 64];   // [dbuf][half][row*64 + swizzled col]
    __shared__ u16 Bs[2][2][128 * 64];

    const int tid = threadIdx.x;
    const int lane = tid & 63;
    const int wid = tid >> 6;        // 0..7
    const int wm = wid >> 2;         // 0..1  (M half)
    const int wn = wid & 3;          // 0..3  (N quarter = one head)
    const int r = lane & 15;
    const int gq = lane >> 4;

    // T1: bijective XCD swizzle (512 blocks, 512%8==0), bx-chunked per XCD
    const int wg = blockIdx.x;
    const int swz = (wg & 7) * 64 + (wg >> 3);
    const int bx = swz >> 3;         // 0..63 (M tile)
    const int by = swz & 7;          // 0..7  (N tile)
    const int m0 = bx * 256;
    const int n0 = by * 256;

    // staging: thread -> (row, slot); T2 inverse-swizzle on the GLOBAL source col
    const int srow = tid >> 3;                       // 0..63
    const int scol = ((tid & 7) ^ (srow & 7)) * 8;   // swizzled 8-elem slot
    const u16* aSrc = A + (size_t)(m0 + srow) * 1024 + scol;
    const u16* bSrc = Bt + (size_t)(n0 + srow) * 1024 + scol;

#define GL(gp, lp) __builtin_amdgcn_global_load_lds(                                  \
        (const __attribute__((address_space(1))) void*)(gp),                          \
        (__attribute__((address_space(3))) void*)(lp), 16, 0, 0)
#define STAGE_A(D, HHH, KT) do {                                                      \
        const u16* g0 = aSrc + (size_t)(HHH) * 128 * 1024 + (KT);                     \
        u16* l0 = &As[D][HHH][tid * 8];                                               \
        GL(g0, l0); GL(g0 + 64 * 1024, l0 + 512 * 8);                                 \
    } while (0)
#define STAGE_B(D, HHH, KT) do {                                                      \
        const u16* g0 = bSrc + (size_t)(HHH) * 128 * 1024 + (KT);                     \
        u16* l0 = &Bs[D][HHH][tid * 8];                                               \
        GL(g0, l0); GL(g0 + 64 * 1024, l0 + 512 * 8);                                 \
    } while (0)

    f32x4 acc[8][4];                 // [mh*4+mi][nh*2+ni]
    #pragma unroll
    for (int i = 0; i < 8; ++i)
        #pragma unroll
        for (int j = 0; j < 4; ++j)
            acc[i][j] = (f32x4){0.f, 0.f, 0.f, 0.f};

    // per-lane swizzled read slots (T2): logical slot = ks*4+gq, physical = ^(r&7)
    const int sk0 = ((gq) ^ (r & 7)) * 8;
    const int sk1 = ((4 + gq) ^ (r & 7)) * 8;
    const int brow = (wn & 1) * 64;  // B row base within its half

    bf16x8 a[4][2], b0[2][2], b1[2][2];

#define LD(p) (*(const bf16x8*)(p))
#define LGKM0 do { asm volatile("s_waitcnt lgkmcnt(0)" ::: "memory");                 \
                   __builtin_amdgcn_sched_barrier(0); } while (0)
#define MFMA_QUAD(MH, NH, BREG) do {                                                  \
        __builtin_amdgcn_s_setprio(1);                                                \
        _Pragma("unroll")                                                             \
        for (int ks = 0; ks < 2; ++ks)                                                \
            _Pragma("unroll")                                                         \
            for (int mi = 0; mi < 4; ++mi)                                            \
                _Pragma("unroll")                                                     \
                for (int ni = 0; ni < 2; ++ni)                                        \
                    acc[(MH)*4+mi][(NH)*2+ni] = __builtin_amdgcn_mfma_f32_16x16x32_bf16( \
                        a[mi][ks], (BREG)[ni][ks], acc[(MH)*4+mi][(NH)*2+ni], 0, 0, 0); \
        __builtin_amdgcn_s_setprio(0);                                                \
    } while (0)

    // prologue: K-tile 0 (all 4 halves) + K-tile 1 A-halves (the "group -1 ph4" job)
    STAGE_A(0, 0, 0); STAGE_A(0, 1, 0); STAGE_B(0, 0, 0); STAGE_B(0, 1, 0);
    STAGE_A(1, 0, 64); STAGE_A(1, 1, 64);
    asm volatile("s_waitcnt vmcnt(4)" ::: "memory");
    __builtin_amdgcn_sched_barrier(0);
    __builtin_amdgcn_s_barrier();

#define GROUP(G, D, DN) do {                                                          \
        const u16* apd = &As[D][wm][0];                                               \
        const u16* bpd = &Bs[D][wn >> 1][0];                                          \
        const int kt1 = ((G) + 1) * 64, kt2 = ((G) + 2) * 64;                         \
        /* ---- phase 1 ---- */                                                       \
        _Pragma("unroll")                                                             \
        for (int mi = 0; mi < 4; ++mi) {                                              \
            a[mi][0] = LD(apd + (mi * 16 + r) * 64 + sk0);                            \
            a[mi][1] = LD(apd + (mi * 16 + r) * 64 + sk1);                            \
        }                                                                             \
        _Pragma("unroll")                                                             \
        for (int ni = 0; ni < 2; ++ni) {                                              \
            b0[ni][0] = LD(bpd + (brow + ni * 16 + r) * 64 + sk0);                    \
            b0[ni][1] = LD(bpd + (brow + ni * 16 + r) * 64 + sk1);                    \
        }                                                                             \
        if (kt1 < 1024) STAGE_B(DN, 0, kt1);                                          \
        __builtin_amdgcn_s_barrier();                                                 \
        LGKM0;                                                                        \
        MFMA_QUAD(0, 0, b0);                                                          \
        __builtin_amdgcn_s_barrier();                                                 \
        /* ---- phase 2 ---- */                                                       \
        _Pragma("unroll")                                                             \
        for (int ni = 0; ni < 2; ++ni) {                                              \
            b1[ni][0] = LD(bpd + (brow + 32 + ni * 16 + r) * 64 + sk0);               \
            b1[ni][1] = LD(bpd + (brow + 32 + ni * 16 + r) * 64 + sk1);               \
        }                                                                             \
        if (kt1 < 1024) STAGE_B(DN, 1, kt1);                                          \
        __builtin_amdgcn_s_barrier();                                                 \
        LGKM0;                                                                        \
        MFMA_QUAD(0, 1, b1);                                                          \
        __builtin_amdgcn_s_barrier();                                                 \
        /* ---- phase 3 ---- */                                                       \
        _Pragma("unroll")                                                             \
        for (int mi = 0; mi < 4; ++mi) {                                              \
            a[mi][0] = LD(apd + (64 + mi * 16 + r) * 64 + sk0);                       \
            a[mi][1] = LD(apd + (64 + mi * 16 + r) * 64 + sk1);                       \
        }                                                                             \
        __builtin_amdgcn_s_barrier();                                                 \
        LGKM0;                                                                        \
        MFMA_QUAD(1, 1, b1);                                                          \
        __builtin_amdgcn_s_barrier();                                                 \
        /* ---- phase 4 ---- */                                                       \
        if (kt2 < 1024) { STAGE_A(D, 0, kt2); STAGE_A(D, 1, kt2); }                   \
        MFMA_QUAD(1, 0, b0);                                                          \
        if (kt2 < 1024)      { asm volatile("s_waitcnt vmcnt(4)" ::: "memory"); }     \
        else if (kt1 < 1024) { asm volatile("s_waitcnt vmcnt(0)" ::: "memory"); }     \
        __builtin_amdgcn_sched_barrier(0);                                            \
        __builtin_amdgcn_s_barrier();                                                 \
    } while (0)

    for (int g = 0; g < 16; g += 2) {
        GROUP(g, 0, 1);
        GROUP(g + 1, 1, 0);
    }
#undef GROUP
#undef MFMA_QUAD
#undef LGKM0
#undef LD
#undef STAGE_A
#undef STAGE_B
#undef GL

    // fused epilogue. Wave (wm,wn): rows m0+wm*128+mh*64+mi*16+gq*4+rr,
    // cols n0+wn*64+nh*32+ni*16+r (wave's 64 cols = exactly one head).
    if (by < 4) {
        const int h = by * 4 + wn;
        #pragma unroll
        for (int mh = 0; mh < 2; ++mh)
            #pragma unroll
            for (int mi = 0; mi < 4; ++mi)
                #pragma unroll
                for (int rr = 0; rr < 4; ++rr) {
                    float s = elu1(acc[mh * 4 + mi][0][rr]) + elu1(acc[mh * 4 + mi][1][rr]) +
                              elu1(acc[mh * 4 + mi][2][rr]) + elu1(acc[mh * 4 + mi][3][rr]);
                    s += __shfl_xor(s, 1); s += __shfl_xor(s, 2);
                    s += __shfl_xor(s, 4); s += __shfl_xor(s, 8);
                    if (r == 0)
                        qsum[(size_t)(m0 + wm * 128 + mh * 64 + mi * 16 + gq * 4 + rr) * 16 + h] = s;
                }
    } else {
        const int h = (by - 4) * 4 + wn;
        const int b = m0 >> 12;
        float kvp[4] = {0.f, 0.f, 0.f, 0.f};
        #pragma unroll
        for (int mh = 0; mh < 2; ++mh)
            #pragma unroll
            for (int mi = 0; mi < 4; ++mi)
                #pragma unroll
                for (int rr = 0; rr < 4; ++rr) {
                    const int row = m0 + wm * 128 + mh * 64 + mi * 16 + gq * 4 + rr;
                    const float vs = vsum[(size_t)row * 16 + h];
                    #pragma unroll
                    for (int nj = 0; nj < 4; ++nj)
                        kvp[nj] += elu1(acc[mh * 4 + mi][nj][rr]) * vs;
                }
        #pragma unroll
        for (int nj = 0; nj < 4; ++nj) {
            kvp[nj] += __shfl_xor(kvp[nj], 16);
            kvp[nj] += __shfl_xor(kvp[nj], 32);
        }
        if (gq == 0) {
            #pragma unroll
            for (int nj = 0; nj < 4; ++nj)
                atomicAdd(&kvsum[((size_t)b * 16 + h) * 64 + (nj >> 1) * 32 + (nj & 1) * 16 + r],
                          kvp[nj]);
        }
    }
}

// ---------------- Wkv[b][h][c] = sum_d kvrow[b][h][d] * W_proj[h*64+d][c] ----------------
__global__ __launch_bounds__(256) void wkv_kernel(const float* __restrict__ kvsum,
                                                  const float* __restrict__ Wproj,
                                                  float* __restrict__ wkv) {
    __shared__ float kv[64];
    const int bh = blockIdx.y;                     // 0..63
    const int c = blockIdx.x * 256 + threadIdx.x;  // 0..1023
    if (threadIdx.x < 64) kv[threadIdx.x] = kvsum[bh * 64 + threadIdx.x];
    __syncthreads();
    const int h = bh & 15;
    float s = 0.f;
    #pragma unroll 8
    for (int d = 0; d < 64; ++d)
        s += kv[d] * Wproj[(size_t)(h * 64 + d) * 1024 + c];
    wkv[(size_t)bh * 1024 + c] = s;
}

// ---------------- y[row][c] = b_proj[c] + sum_h qsum[row][h] * Wkv[b][h][c] ----------------
__global__ __launch_bounds__(256) void final_kernel(const float* __restrict__ qsum,
                                                    const float* __restrict__ wkv,
                                                    const float* __restrict__ bproj,
                                                    float* __restrict__ y) {
    __shared__ float qs[4][16];
    const int r0 = blockIdx.x * 4;                 // 4096 blocks, 4 rows each
    const int t = threadIdx.x;
    if (t < 64) qs[t >> 4][t & 15] = qsum[(size_t)(r0 + (t >> 4)) * 16 + (t & 15)];
    __syncthreads();
    const int b = r0 >> 12;
    const f32x4* wk4 = (const f32x4*)(wkv + (size_t)b * 16 * 1024);
    f32x4 bp = ((const f32x4*)bproj)[t];
    f32x4 a0 = bp, a1 = bp, a2 = bp, a3 = bp;
    #pragma unroll
    for (int h = 0; h < 16; ++h) {
        f32x4 w = wk4[h * 256 + t];
        a0 += qs[0][h] * w;
        a1 += qs[1][h] * w;
        a2 += qs[2][h] * w;
        a3 += qs[3][h] * w;
    }
    f32x4* y4 = (f32x4*)y;
    y4[(size_t)(r0 + 0) * 256 + t] = a0;
    y4[(size_t)(r0 + 1) * 256 + t] = a1;
    y4[(size_t)(r0 + 2) * 256 + t] = a2;
    y4[(size_t)(r0 + 3) * 256 + t] = a3;
}

extern "C" void kernel_launch(void* const* d_in, const int* in_sizes, int n_in,
                              void* d_out, int out_size, void* d_ws, size_t ws_size,
                              hipStream_t stream) {
    const float* x     = (const float*)d_in[0];   // [4,4096,1024]
    const float* Wqkv  = (const float*)d_in[1];   // [1024,3072]
    const float* Wproj = (const float*)d_in[2];   // [1024,1024]
    const float* bproj = (const float*)d_in[3];   // [1024]
    float* y = (float*)d_out;                     // [4,4096,1024]

    char* ws = (char*)d_ws;
    u16*   xb    = (u16*)(ws);                    // 16384*1024*2 = 33554432
    u16*   wqkt  = (u16*)(ws + 33554432);         // 2048*1024*2  =  4194304
    u16*   wvst  = (u16*)(ws + 37748736);         // 16*1024*2    =    32768
    float* vsum  = (float*)(ws + 37781504);       // 16384*16*4   =  1048576
    float* qsum  = (float*)(ws + 38830080);       // 16384*16*4   =  1048576
    float* kvsum = (float*)(ws + 39878656);       // 4*16*64*4    =    16384
    float* wkv   = (float*)(ws + 39895040);       // 4*16*1024*4  =   262144
    // total 40157184 bytes (~38.3 MiB)

    hipMemsetAsync(kvsum, 0, 4096 * sizeof(float), stream);

    cast_x_kernel<<<4096, 256, 0, stream>>>(x, xb, (MTOT * CC) / 4);
    wsum_kernel<<<1024, 256, 0, stream>>>(Wqkv, wvst);
    trans_wqk_kernel<<<dim3(64, 32), dim3(32, 8), 0, stream>>>(Wqkv, wqkt);
    vsum_kernel<<<256, 256, 0, stream>>>(xb, wvst, vsum);
    gemm_qk_kernel<<<512, 512, 0, stream>>>(xb, wqkt, vsum, qsum, kvsum);
    wkv_kernel<<<dim3(4, 64), 256, 0, stream>>>(kvsum, Wproj, wkv);
    final_kernel<<<4096, 256, 0, stream>>>(qsum, wkv, bproj, y);
}